// Round 9
// baseline (561.064 us; speedup 1.0000x reference)
//
#include <hip/hip_runtime.h>
#include <math.h>

#define BATCH 8
#define NNODE 2048
#define DIN   1024
#define DM    256
#define ROWS_TOTAL (BATCH * NNODE)   // 16384

#define Q127  0.011359803471566641f   // log2(e) / 127  ->  exp2(q*Q127) = e^(q/127)
#define INV127 0.007874015748031496f  // 1/127

typedef unsigned short u16;
typedef __attribute__((ext_vector_type(8))) short short8;   // 8 bf16
typedef __attribute__((ext_vector_type(4))) float f32x4;

__device__ __forceinline__ u16 f2b(float f) {   // fp32 -> bf16 RNE
    union { float f; unsigned u; } v; v.f = f;
    unsigned r = v.u + 0x7fffu + ((v.u >> 16) & 1u);
    return (u16)(r >> 16);
}
// signed byte k (0..3) of dword -> float
__device__ __forceinline__ float dqi(unsigned wd, int k) {
    return (float)((int)(wd << ((3 - k) * 8)) >> 24);
}

// ---------------------------------------------------------------------------
// Kernel 0: Wt[c][k] = bf16(W[k][c]); also initializes the 6 colsum ping
// buffers: buf0 = 1.0 (iteration-1 "exp(-v)" = 1), buf1..buf5 = 0 (atomic
// accumulation targets).
// ---------------------------------------------------------------------------
__global__ __launch_bounds__(256) void cvgm_prep_w(
    const float* __restrict__ W, u16* __restrict__ Wt, float* __restrict__ bufs)
{
    const int gid = (blockIdx.y * 32 + blockIdx.x) * 256 + threadIdx.x;  // 0..65535
    for (int i = gid; i < 6 * ROWS_TOTAL; i += 65536)
        bufs[i] = (i < ROWS_TOTAL) ? 1.0f : 0.0f;

    __shared__ float t[32][33];
    const int tx = threadIdx.x & 31, ty = threadIdx.x >> 5;
    const int k0 = blockIdx.x * 32, c0 = blockIdx.y * 32;
    #pragma unroll
    for (int r = 0; r < 4; ++r) {
        const int kl = ty * 4 + r;
        t[kl][tx] = W[(size_t)(k0 + kl) * DM + c0 + tx];
    }
    __syncthreads();
    #pragma unroll
    for (int r = 0; r < 4; ++r) {
        const int cl = ty * 4 + r;
        Wt[(size_t)(c0 + cl) * DIN + k0 + tx] = f2b(t[tx][cl]);
    }
}

// ---------------------------------------------------------------------------
// Kernel 1: P = bf16(l2norm(X@W + b)).  64 rows x 256 cols per block,
// 512 threads = 8 waves, BK=64.  grid (256, 2): y selects drone/sat.
// ---------------------------------------------------------------------------
__global__ __launch_bounds__(512) void cvgm_proj_mfma(
    const float* __restrict__ Xd, const float* __restrict__ Xs,
    const u16* __restrict__ Wt, const float* __restrict__ bias,
    u16* __restrict__ Pd, u16* __restrict__ Ps)
{
    __shared__ u16 As[64 * 64];     // 8 KB  chunk-swizzled [row][k]
    __shared__ u16 Bs[256 * 64];    // 32 KB chunk-swizzled [col][k]
    __shared__ float rsum[4][64];

    const float* X = blockIdx.y ? Xs : Xd;
    u16* P = blockIdx.y ? Ps : Pd;

    const int tid = threadIdx.x;
    const int lane = tid & 63, wid = tid >> 6;
    const int wr = wid >> 2, wc = wid & 3;
    const int l15 = lane & 15, l4 = lane >> 4;
    const int row0 = blockIdx.x * 64;

    f32x4 acc[2][4];
    #pragma unroll
    for (int m = 0; m < 2; ++m)
        #pragma unroll
        for (int n = 0; n < 4; ++n) acc[m][n] = (f32x4){0.f, 0.f, 0.f, 0.f};

    const int arow = tid >> 3, ac = tid & 7;   // A: 1 short8 chunk / thread

    for (int k0 = 0; k0 < DIN; k0 += 64) {
        const float* src = X + (size_t)(row0 + arow) * DIN + k0 + ac * 8;
        const float4 x0 = *(const float4*)src;
        const float4 x1 = *(const float4*)(src + 4);
        short8 wb[4];
        #pragma unroll
        for (int it = 0; it < 4; ++it) {
            const int id = it * 512 + tid;
            const int col = id >> 3, cc = id & 7;
            wb[it] = *(const short8*)(Wt + (size_t)col * DIN + k0 + cc * 8);
        }
        __syncthreads();
        short8 ap;
        ap[0]=(short)f2b(x0.x); ap[1]=(short)f2b(x0.y); ap[2]=(short)f2b(x0.z); ap[3]=(short)f2b(x0.w);
        ap[4]=(short)f2b(x1.x); ap[5]=(short)f2b(x1.y); ap[6]=(short)f2b(x1.z); ap[7]=(short)f2b(x1.w);
        *(short8*)(As + (arow * 8 + (ac ^ (arow & 7))) * 8) = ap;
        #pragma unroll
        for (int it = 0; it < 4; ++it) {
            const int id = it * 512 + tid;
            const int col = id >> 3, cc = id & 7;
            *(short8*)(Bs + (col * 8 + (cc ^ (col & 7))) * 8) = wb[it];
        }
        __syncthreads();
        #pragma unroll
        for (int ks = 0; ks < 2; ++ks) {
            const int ch = ks * 4 + l4;
            short8 af[2], bfr[4];
            #pragma unroll
            for (int m = 0; m < 2; ++m) {
                const int row = wr * 32 + m * 16 + l15;
                af[m] = *(const short8*)(As + (row * 8 + (ch ^ (row & 7))) * 8);
            }
            #pragma unroll
            for (int n = 0; n < 4; ++n) {
                const int col = wc * 64 + n * 16 + l15;
                bfr[n] = *(const short8*)(Bs + (col * 8 + (ch ^ (col & 7))) * 8);
            }
            #pragma unroll
            for (int m = 0; m < 2; ++m)
                #pragma unroll
                for (int n = 0; n < 4; ++n)
                    acc[m][n] = __builtin_amdgcn_mfma_f32_16x16x32_bf16(af[m], bfr[n], acc[m][n], 0, 0, 0);
        }
        __syncthreads();
    }

    #pragma unroll
    for (int n = 0; n < 4; ++n) {
        const float bv = bias[wc * 64 + n * 16 + l15];
        #pragma unroll
        for (int m = 0; m < 2; ++m)
            #pragma unroll
            for (int r = 0; r < 4; ++r) acc[m][n][r] += bv;
    }
    #pragma unroll
    for (int m = 0; m < 2; ++m)
        #pragma unroll
        for (int r = 0; r < 4; ++r) {
            float s = 0.f;
            #pragma unroll
            for (int n = 0; n < 4; ++n) s += acc[m][n][r] * acc[m][n][r];
            s += __shfl_xor(s, 1); s += __shfl_xor(s, 2);
            s += __shfl_xor(s, 4); s += __shfl_xor(s, 8);
            if (l15 == 0) rsum[wc][wr * 32 + m * 16 + l4 * 4 + r] = s;
        }
    __syncthreads();
    #pragma unroll
    for (int m = 0; m < 2; ++m)
        #pragma unroll
        for (int r = 0; r < 4; ++r) {
            const int row = wr * 32 + m * 16 + l4 * 4 + r;
            const float tot = rsum[0][row] + rsum[1][row] + rsum[2][row] + rsum[3][row];
            const float inv = 1.0f / fmaxf(sqrtf(tot), 1e-12f);
            #pragma unroll
            for (int n = 0; n < 4; ++n) {
                const int col = wc * 64 + n * 16 + l15;
                P[(size_t)(row0 + row) * DM + col] = f2b(acc[m][n][r] * inv);
            }
        }
}

// ---------------------------------------------------------------------------
// Kernel 2: M0q[b] = int8( 127 * D[b]@S[b]^T )  bf16 MFMA 128x128 tile.
// ---------------------------------------------------------------------------
__global__ __launch_bounds__(256) void cvgm_m0_mfma(
    const u16* __restrict__ Dp, const u16* __restrict__ Sp,
    char* __restrict__ Cq)
{
    __shared__ u16 As[128 * 64];
    __shared__ u16 Bs[128 * 64];

    const int tid = threadIdx.x;
    const int lane = tid & 63, wid = tid >> 6;
    const int wr = wid >> 1, wc = wid & 1;
    const int l15 = lane & 15, l4 = lane >> 4;
    const int bb = blockIdx.z;
    const int i0 = blockIdx.y * 128, j0 = blockIdx.x * 128;
    const u16* Db = Dp + (size_t)bb * NNODE * DM;
    const u16* Sb = Sp + (size_t)bb * NNODE * DM;

    f32x4 acc[4][4];
    #pragma unroll
    for (int m = 0; m < 4; ++m)
        #pragma unroll
        for (int n = 0; n < 4; ++n) acc[m][n] = (f32x4){0.f, 0.f, 0.f, 0.f};

    for (int k0 = 0; k0 < DM; k0 += 64) {
        short8 ra[4], rb[4];
        #pragma unroll
        for (int it = 0; it < 4; ++it) {
            const int id = it * 256 + tid;
            const int row = id >> 3, c = id & 7;
            ra[it] = *(const short8*)(Db + (size_t)(i0 + row) * DM + k0 + c * 8);
            rb[it] = *(const short8*)(Sb + (size_t)(j0 + row) * DM + k0 + c * 8);
        }
        __syncthreads();
        #pragma unroll
        for (int it = 0; it < 4; ++it) {
            const int id = it * 256 + tid;
            const int row = id >> 3, c = id & 7;
            const int sl = row * 8 + (c ^ (row & 7));
            *(short8*)(As + sl * 8) = ra[it];
            *(short8*)(Bs + sl * 8) = rb[it];
        }
        __syncthreads();
        #pragma unroll
        for (int ks = 0; ks < 2; ++ks) {
            const int ch = ks * 4 + l4;
            short8 af[4], bfr[4];
            #pragma unroll
            for (int m = 0; m < 4; ++m) {
                const int row = wr * 64 + m * 16 + l15;
                af[m] = *(const short8*)(As + (row * 8 + (ch ^ (row & 7))) * 8);
            }
            #pragma unroll
            for (int n = 0; n < 4; ++n) {
                const int col = wc * 64 + n * 16 + l15;
                bfr[n] = *(const short8*)(Bs + (col * 8 + (ch ^ (col & 7))) * 8);
            }
            #pragma unroll
            for (int m = 0; m < 4; ++m)
                #pragma unroll
                for (int n = 0; n < 4; ++n)
                    acc[m][n] = __builtin_amdgcn_mfma_f32_16x16x32_bf16(af[m], bfr[n], acc[m][n], 0, 0, 0);
        }
        __syncthreads();
    }

    char* Cqb = Cq + (size_t)bb * NNODE * NNODE;
    #pragma unroll
    for (int m = 0; m < 4; ++m) {
        const int row = i0 + wr * 64 + m * 16 + l4 * 4;
        #pragma unroll
        for (int n = 0; n < 4; ++n) {
            const int col = j0 + wc * 64 + n * 16 + l15;
            #pragma unroll
            for (int r = 0; r < 4; ++r) {
                int q = __float2int_rn(acc[m][n][r] * 127.f);
                q = q > 127 ? 127 : (q < -127 ? -127 : q);
                Cqb[(size_t)(row + r) * NNODE + col] = (char)q;
            }
        }
    }
}

// ---------------------------------------------------------------------------
// Kernel 3: one Sinkhorn iteration, fully multiplicative (no logs).
// grid (128, 8), 256 threads, 16-row stripe per block.
//   wv[j]   = 1 / Sin[j]                (col factor from previous iteration)
//   row:  S = sum_j p*wv  (butterfly);  eu = 1/S;  euo[row] = eu
//   col:  sc[j] += p*eu;  block-merge in LDS;  atomicAdd -> Sout[j]
// Sout must be pre-zeroed; kernel boundary orders atomics for next iter.
// ---------------------------------------------------------------------------
template <int FIRST>
__global__ __launch_bounds__(256) void cvgm_rc(
    const char* __restrict__ Mq, const float* __restrict__ Sin,
    float* __restrict__ Sout, float* __restrict__ euo)
{
    __shared__ float cps[4][NNODE];   // 32 KB per-wave column partials

    const int tid = threadIdx.x;
    const int lane = tid & 63, w = tid >> 6;
    const int b = blockIdx.y, chunk = blockIdx.x;
    const size_t row0 = ((size_t)b << 11) + chunk * 16;
    const char* gb = Mq + row0 * NNODE + lane * 16;

    // wv = 1/colsum at this thread's 32 cols (col = seg*1024 + lane*16 + k)
    float wv[32];
    if constexpr (FIRST) {
        #pragma unroll
        for (int k = 0; k < 32; ++k) wv[k] = 1.f;
    } else {
        const float* Sb = Sin + (b << 11);
        #pragma unroll
        for (int s = 0; s < 2; ++s)
            #pragma unroll
            for (int k = 0; k < 4; ++k) {
                const float4 vv = *(const float4*)(Sb + s * 1024 + lane * 16 + k * 4);
                wv[s*16+k*4+0] = 1.0f / vv.x;
                wv[s*16+k*4+1] = 1.0f / vv.y;
                wv[s*16+k*4+2] = 1.0f / vv.z;
                wv[s*16+k*4+3] = 1.0f / vv.w;
            }
    }

    float sc[32];
    #pragma unroll
    for (int k = 0; k < 32; ++k) sc[k] = 0.f;

    #pragma unroll
    for (int rr = 0; rr < 4; ++rr) {
        const char* rsrc = gb + (size_t)(w * 4 + rr) * NNODE;
        const int4 d0 = *(const int4*)(rsrc);
        const int4 d1 = *(const int4*)(rsrc + 1024);
        const unsigned qd[8] = {(unsigned)d0.x, (unsigned)d0.y, (unsigned)d0.z, (unsigned)d0.w,
                                (unsigned)d1.x, (unsigned)d1.y, (unsigned)d1.z, (unsigned)d1.w};
        float p[32];
        #pragma unroll
        for (int q = 0; q < 8; ++q)
            #pragma unroll
            for (int k = 0; k < 4; ++k)
                p[q * 4 + k] = exp2f(dqi(qd[q], k) * Q127);
        float s = 0.f;
        #pragma unroll
        for (int k = 0; k < 32; ++k) s = fmaf(p[k], wv[k], s);
        #pragma unroll
        for (int off = 1; off < 64; off <<= 1) s += __shfl_xor(s, off);
        const float eu = 1.0f / s;
        if (lane == 0) euo[row0 + w * 4 + rr] = eu;
        #pragma unroll
        for (int k = 0; k < 32; ++k) sc[k] = fmaf(p[k], eu, sc[k]);
    }

    #pragma unroll
    for (int s = 0; s < 2; ++s)
        #pragma unroll
        for (int k = 0; k < 4; ++k)
            *(float4*)(&cps[w][s * 1024 + lane * 16 + k * 4]) =
                make_float4(sc[s*16+k*4+0], sc[s*16+k*4+1], sc[s*16+k*4+2], sc[s*16+k*4+3]);
    __syncthreads();

    // block merge of 4 waves, then device-scope atomic accumulate into Sout
    const int j = tid * 8;
    float4 a0 = *(const float4*)(&cps[0][j]), a1 = *(const float4*)(&cps[0][j + 4]);
    #pragma unroll
    for (int ww = 1; ww < 4; ++ww) {
        const float4 b0 = *(const float4*)(&cps[ww][j]);
        const float4 b1 = *(const float4*)(&cps[ww][j + 4]);
        a0.x += b0.x; a0.y += b0.y; a0.z += b0.z; a0.w += b0.w;
        a1.x += b1.x; a1.y += b1.y; a1.z += b1.z; a1.w += b1.w;
    }
    float* dst = Sout + (b << 11) + j;
    atomicAdd(dst + 0, a0.x); atomicAdd(dst + 1, a0.y);
    atomicAdd(dst + 2, a0.z); atomicAdd(dst + 3, a0.w);
    atomicAdd(dst + 4, a1.x); atomicAdd(dst + 5, a1.y);
    atomicAdd(dst + 6, a1.z); atomicAdd(dst + 7, a1.w);
}

// ---------------------------------------------------------------------------
// Kernel 4: assignment = p * eu * wv -> out fp32; spart[row] partial score.
// Same stripe geometry as cvgm_rc: grid (128, 8), 256 threads.
// ---------------------------------------------------------------------------
__global__ __launch_bounds__(256) void cvgm_final(
    const char* __restrict__ Mq, const float* __restrict__ eui,
    const float* __restrict__ Scol, float* __restrict__ out,
    float* __restrict__ spart)
{
    const int tid = threadIdx.x;
    const int lane = tid & 63, w = tid >> 6;
    const int b = blockIdx.y, chunk = blockIdx.x;
    const size_t row0 = ((size_t)b << 11) + chunk * 16;
    const char* gb = Mq + row0 * NNODE + lane * 16;

    float wv[32];
    {
        const float* Sb = Scol + (b << 11);
        #pragma unroll
        for (int s = 0; s < 2; ++s)
            #pragma unroll
            for (int k = 0; k < 4; ++k) {
                const float4 vv = *(const float4*)(Sb + s * 1024 + lane * 16 + k * 4);
                wv[s*16+k*4+0] = 1.0f / vv.x;
                wv[s*16+k*4+1] = 1.0f / vv.y;
                wv[s*16+k*4+2] = 1.0f / vv.z;
                wv[s*16+k*4+3] = 1.0f / vv.w;
            }
    }

    #pragma unroll
    for (int rr = 0; rr < 4; ++rr) {
        const size_t row = row0 + w * 4 + rr;
        const char* rsrc = gb + (size_t)(w * 4 + rr) * NNODE;
        float* drow = out + row * NNODE + lane * 16;
        const float eu = eui[row];
        const int4 d0 = *(const int4*)(rsrc);
        const int4 d1 = *(const int4*)(rsrc + 1024);
        const unsigned qd[8] = {(unsigned)d0.x, (unsigned)d0.y, (unsigned)d0.z, (unsigned)d0.w,
                                (unsigned)d1.x, (unsigned)d1.y, (unsigned)d1.z, (unsigned)d1.w};
        float acc = 0.f;
        #pragma unroll
        for (int q = 0; q < 8; ++q) {
            float e[4];
            #pragma unroll
            for (int k = 0; k < 4; ++k) {
                const float xq = dqi(qd[q], k);
                e[k] = exp2f(xq * Q127) * eu * wv[q * 4 + k];
                acc = fmaf(e[k], xq, acc);
            }
            *(float4*)(drow + (q >> 2) * 1024 + (q & 3) * 4) = make_float4(e[0], e[1], e[2], e[3]);
        }
        #pragma unroll
        for (int off = 1; off < 64; off <<= 1) acc += __shfl_xor(acc, off);
        if (lane == 0) spart[row] = acc * INV127;
    }
}

// ---------------------------------------------------------------------------
// Kernel 5: match_score[b] = sum(spart[b,:]) / 2048
// ---------------------------------------------------------------------------
__global__ __launch_bounds__(256) void cvgm_score(
    const float* __restrict__ spart, float* __restrict__ score)
{
    const int b = blockIdx.x;
    float acc = 0.f;
    for (int t = threadIdx.x; t < NNODE; t += 256) acc += spart[(b << 11) + t];
    #pragma unroll
    for (int off = 1; off < 64; off <<= 1) acc += __shfl_xor(acc, off);
    __shared__ float sh[4];
    if ((threadIdx.x & 63) == 0) sh[threadIdx.x >> 6] = acc;
    __syncthreads();
    if (threadIdx.x == 0) score[b] = (sh[0] + sh[1] + sh[2] + sh[3]) * (1.0f / 2048.0f);
}

// ---------------------------------------------------------------------------
extern "C" void kernel_launch(void* const* d_in, const int* in_sizes, int n_in,
                              void* d_out, int out_size, void* d_ws, size_t ws_size,
                              hipStream_t stream) {
    (void)in_sizes; (void)n_in; (void)out_size; (void)ws_size;
    const float* drone = (const float*)d_in[0];
    const float* sat   = (const float*)d_in[1];
    const float* W     = (const float*)d_in[2];
    const float* bias  = (const float*)d_in[3];

    float* out   = (float*)d_out;
    float* score = out + (size_t)BATCH * NNODE * NNODE;

    char* ws = (char*)d_ws;
    const size_t SZ_M0Q  = (size_t)BATCH * NNODE * NNODE;       // 32 MiB
    const size_t SZ_PROJ = (size_t)ROWS_TOTAL * DM * 2;         // 8 MiB
    const size_t SZ_WT   = (size_t)DM * DIN * 2;                // 512 KiB
    const size_t SZ_UV   = (size_t)ROWS_TOTAL * 4;              // 64 KiB

    size_t off = 0;
    char* M0q  = ws + off;            off += SZ_M0Q;
    u16* dproj = (u16*)(ws + off);    off += SZ_PROJ;
    u16* sproj = (u16*)(ws + off);    off += SZ_PROJ;
    u16* Wt    = (u16*)(ws + off);    off += SZ_WT;
    float* bufs = (float*)(ws + off); off += 6 * SZ_UV;   // colsum ping chain
    float* eu   = (float*)(ws + off); off += SZ_UV;
    float* spart = (float*)(ws + off);

    cvgm_prep_w<<<dim3(32, 8), 256, 0, stream>>>(W, Wt, bufs);
    cvgm_proj_mfma<<<dim3(256, 2), 512, 0, stream>>>(drone, sat, Wt, bias, dproj, sproj);
    cvgm_m0_mfma<<<dim3(16, 16, 8), 256, 0, stream>>>(dproj, sproj, M0q);

    // 5 multiplicative Sinkhorn iterations; colsum chain buf[it] -> buf[it+1]
    cvgm_rc<1><<<dim3(128, 8), 256, 0, stream>>>(M0q, bufs, bufs + ROWS_TOTAL, eu);
    for (int it = 1; it < 5; ++it)
        cvgm_rc<0><<<dim3(128, 8), 256, 0, stream>>>(
            M0q, bufs + (size_t)it * ROWS_TOTAL, bufs + (size_t)(it + 1) * ROWS_TOTAL, eu);

    cvgm_final<<<dim3(128, 8), 256, 0, stream>>>(M0q, eu, bufs + 5 * (size_t)ROWS_TOTAL, out, spart);
    cvgm_score<<<BATCH, 256, 0, stream>>>(spart, score);
}

// Round 10
// 261.328 us; speedup vs baseline: 2.1470x; 2.1470x over previous
//
#include <hip/hip_runtime.h>
#include <math.h>

#define BATCH 8
#define NNODE 2048
#define DIN   1024
#define DM    256
#define ROWS_TOTAL (BATCH * NNODE)   // 16384

#define Q127  0.011359803471566641f   // log2(e) / 127  ->  exp2(q*Q127) = e^(q/127)
#define INV127 0.007874015748031496f  // 1/127

typedef unsigned short u16;
typedef __attribute__((ext_vector_type(8))) short short8;   // 8 bf16
typedef __attribute__((ext_vector_type(4))) float f32x4;

__device__ __forceinline__ u16 f2b(float f) {   // fp32 -> bf16 RNE
    union { float f; unsigned u; } v; v.f = f;
    unsigned r = v.u + 0x7fffu + ((v.u >> 16) & 1u);
    return (u16)(r >> 16);
}
// signed byte k (0..3) of dword -> float
__device__ __forceinline__ float dqi(unsigned wd, int k) {
    return (float)((int)(wd << ((3 - k) * 8)) >> 24);
}

// ---------------------------------------------------------------------------
// Kernel 0: Wt[c][k] = bf16(W[k][c])   (pure transpose; no buffer init needed)
// ---------------------------------------------------------------------------
__global__ __launch_bounds__(256) void cvgm_prep_w(
    const float* __restrict__ W, u16* __restrict__ Wt)
{
    __shared__ float t[32][33];
    const int tx = threadIdx.x & 31, ty = threadIdx.x >> 5;
    const int k0 = blockIdx.x * 32, c0 = blockIdx.y * 32;
    #pragma unroll
    for (int r = 0; r < 4; ++r) {
        const int kl = ty * 4 + r;
        t[kl][tx] = W[(size_t)(k0 + kl) * DM + c0 + tx];
    }
    __syncthreads();
    #pragma unroll
    for (int r = 0; r < 4; ++r) {
        const int cl = ty * 4 + r;
        Wt[(size_t)(c0 + cl) * DIN + k0 + tx] = f2b(t[tx][cl]);
    }
}

// ---------------------------------------------------------------------------
// Kernel 1: P = bf16(l2norm(X@W + b)).  64 rows x 256 cols per block,
// 512 threads = 8 waves, BK=64.  grid (256, 2): y selects drone/sat.
// ---------------------------------------------------------------------------
__global__ __launch_bounds__(512) void cvgm_proj_mfma(
    const float* __restrict__ Xd, const float* __restrict__ Xs,
    const u16* __restrict__ Wt, const float* __restrict__ bias,
    u16* __restrict__ Pd, u16* __restrict__ Ps)
{
    __shared__ u16 As[64 * 64];     // 8 KB  chunk-swizzled [row][k]
    __shared__ u16 Bs[256 * 64];    // 32 KB chunk-swizzled [col][k]
    __shared__ float rsum[4][64];

    const float* X = blockIdx.y ? Xs : Xd;
    u16* P = blockIdx.y ? Ps : Pd;

    const int tid = threadIdx.x;
    const int lane = tid & 63, wid = tid >> 6;
    const int wr = wid >> 2, wc = wid & 3;
    const int l15 = lane & 15, l4 = lane >> 4;
    const int row0 = blockIdx.x * 64;

    f32x4 acc[2][4];
    #pragma unroll
    for (int m = 0; m < 2; ++m)
        #pragma unroll
        for (int n = 0; n < 4; ++n) acc[m][n] = (f32x4){0.f, 0.f, 0.f, 0.f};

    const int arow = tid >> 3, ac = tid & 7;   // A: 1 short8 chunk / thread

    for (int k0 = 0; k0 < DIN; k0 += 64) {
        const float* src = X + (size_t)(row0 + arow) * DIN + k0 + ac * 8;
        const float4 x0 = *(const float4*)src;
        const float4 x1 = *(const float4*)(src + 4);
        short8 wb[4];
        #pragma unroll
        for (int it = 0; it < 4; ++it) {
            const int id = it * 512 + tid;
            const int col = id >> 3, cc = id & 7;
            wb[it] = *(const short8*)(Wt + (size_t)col * DIN + k0 + cc * 8);
        }
        __syncthreads();
        short8 ap;
        ap[0]=(short)f2b(x0.x); ap[1]=(short)f2b(x0.y); ap[2]=(short)f2b(x0.z); ap[3]=(short)f2b(x0.w);
        ap[4]=(short)f2b(x1.x); ap[5]=(short)f2b(x1.y); ap[6]=(short)f2b(x1.z); ap[7]=(short)f2b(x1.w);
        *(short8*)(As + (arow * 8 + (ac ^ (arow & 7))) * 8) = ap;
        #pragma unroll
        for (int it = 0; it < 4; ++it) {
            const int id = it * 512 + tid;
            const int col = id >> 3, cc = id & 7;
            *(short8*)(Bs + (col * 8 + (cc ^ (col & 7))) * 8) = wb[it];
        }
        __syncthreads();
        #pragma unroll
        for (int ks = 0; ks < 2; ++ks) {
            const int ch = ks * 4 + l4;
            short8 af[2], bfr[4];
            #pragma unroll
            for (int m = 0; m < 2; ++m) {
                const int row = wr * 32 + m * 16 + l15;
                af[m] = *(const short8*)(As + (row * 8 + (ch ^ (row & 7))) * 8);
            }
            #pragma unroll
            for (int n = 0; n < 4; ++n) {
                const int col = wc * 64 + n * 16 + l15;
                bfr[n] = *(const short8*)(Bs + (col * 8 + (ch ^ (col & 7))) * 8);
            }
            #pragma unroll
            for (int m = 0; m < 2; ++m)
                #pragma unroll
                for (int n = 0; n < 4; ++n)
                    acc[m][n] = __builtin_amdgcn_mfma_f32_16x16x32_bf16(af[m], bfr[n], acc[m][n], 0, 0, 0);
        }
        __syncthreads();
    }

    #pragma unroll
    for (int n = 0; n < 4; ++n) {
        const float bv = bias[wc * 64 + n * 16 + l15];
        #pragma unroll
        for (int m = 0; m < 2; ++m)
            #pragma unroll
            for (int r = 0; r < 4; ++r) acc[m][n][r] += bv;
    }
    #pragma unroll
    for (int m = 0; m < 2; ++m)
        #pragma unroll
        for (int r = 0; r < 4; ++r) {
            float s = 0.f;
            #pragma unroll
            for (int n = 0; n < 4; ++n) s += acc[m][n][r] * acc[m][n][r];
            s += __shfl_xor(s, 1); s += __shfl_xor(s, 2);
            s += __shfl_xor(s, 4); s += __shfl_xor(s, 8);
            if (l15 == 0) rsum[wc][wr * 32 + m * 16 + l4 * 4 + r] = s;
        }
    __syncthreads();
    #pragma unroll
    for (int m = 0; m < 2; ++m)
        #pragma unroll
        for (int r = 0; r < 4; ++r) {
            const int row = wr * 32 + m * 16 + l4 * 4 + r;
            const float tot = rsum[0][row] + rsum[1][row] + rsum[2][row] + rsum[3][row];
            const float inv = 1.0f / fmaxf(sqrtf(tot), 1e-12f);
            #pragma unroll
            for (int n = 0; n < 4; ++n) {
                const int col = wc * 64 + n * 16 + l15;
                P[(size_t)(row0 + row) * DM + col] = f2b(acc[m][n][r] * inv);
            }
        }
}

// ---------------------------------------------------------------------------
// Kernel 2: M0q[b] = int8( 127 * D[b]@S[b]^T )  bf16 MFMA 128x128 tile.
// ---------------------------------------------------------------------------
__global__ __launch_bounds__(256) void cvgm_m0_mfma(
    const u16* __restrict__ Dp, const u16* __restrict__ Sp,
    char* __restrict__ Cq)
{
    __shared__ u16 As[128 * 64];
    __shared__ u16 Bs[128 * 64];

    const int tid = threadIdx.x;
    const int lane = tid & 63, wid = tid >> 6;
    const int wr = wid >> 1, wc = wid & 1;
    const int l15 = lane & 15, l4 = lane >> 4;
    const int bb = blockIdx.z;
    const int i0 = blockIdx.y * 128, j0 = blockIdx.x * 128;
    const u16* Db = Dp + (size_t)bb * NNODE * DM;
    const u16* Sb = Sp + (size_t)bb * NNODE * DM;

    f32x4 acc[4][4];
    #pragma unroll
    for (int m = 0; m < 4; ++m)
        #pragma unroll
        for (int n = 0; n < 4; ++n) acc[m][n] = (f32x4){0.f, 0.f, 0.f, 0.f};

    for (int k0 = 0; k0 < DM; k0 += 64) {
        short8 ra[4], rb[4];
        #pragma unroll
        for (int it = 0; it < 4; ++it) {
            const int id = it * 256 + tid;
            const int row = id >> 3, c = id & 7;
            ra[it] = *(const short8*)(Db + (size_t)(i0 + row) * DM + k0 + c * 8);
            rb[it] = *(const short8*)(Sb + (size_t)(j0 + row) * DM + k0 + c * 8);
        }
        __syncthreads();
        #pragma unroll
        for (int it = 0; it < 4; ++it) {
            const int id = it * 256 + tid;
            const int row = id >> 3, c = id & 7;
            const int sl = row * 8 + (c ^ (row & 7));
            *(short8*)(As + sl * 8) = ra[it];
            *(short8*)(Bs + sl * 8) = rb[it];
        }
        __syncthreads();
        #pragma unroll
        for (int ks = 0; ks < 2; ++ks) {
            const int ch = ks * 4 + l4;
            short8 af[4], bfr[4];
            #pragma unroll
            for (int m = 0; m < 4; ++m) {
                const int row = wr * 64 + m * 16 + l15;
                af[m] = *(const short8*)(As + (row * 8 + (ch ^ (row & 7))) * 8);
            }
            #pragma unroll
            for (int n = 0; n < 4; ++n) {
                const int col = wc * 64 + n * 16 + l15;
                bfr[n] = *(const short8*)(Bs + (col * 8 + (ch ^ (col & 7))) * 8);
            }
            #pragma unroll
            for (int m = 0; m < 4; ++m)
                #pragma unroll
                for (int n = 0; n < 4; ++n)
                    acc[m][n] = __builtin_amdgcn_mfma_f32_16x16x32_bf16(af[m], bfr[n], acc[m][n], 0, 0, 0);
        }
        __syncthreads();
    }

    char* Cqb = Cq + (size_t)bb * NNODE * NNODE;
    #pragma unroll
    for (int m = 0; m < 4; ++m) {
        const int row = i0 + wr * 64 + m * 16 + l4 * 4;
        #pragma unroll
        for (int n = 0; n < 4; ++n) {
            const int col = j0 + wc * 64 + n * 16 + l15;
            #pragma unroll
            for (int r = 0; r < 4; ++r) {
                int q = __float2int_rn(acc[m][n][r] * 127.f);
                q = q > 127 ? 127 : (q < -127 ? -127 : q);
                Cqb[(size_t)(row + r) * NNODE + col] = (char)q;
            }
        }
    }
}

// ---------------------------------------------------------------------------
// Kernel 3: one Sinkhorn iteration, multiplicative (no logs), ps-buffer
// reduction (NO atomics -- round-9's memory-side RMW serialization lesson).
// grid (128, 8), 256 threads, 16-row stripe per block.
//   wv[j] = 1 / Sin[j]  (FIRST: wv = 1)
//   row:  s = sum_j p*wv (butterfly); eu = 1/s -> euo[row]
//   col:  sc[j] += p*eu; block merge in LDS -> ps[b*128+chunk][:]
// ---------------------------------------------------------------------------
template <int FIRST>
__global__ __launch_bounds__(256) void cvgm_rc(
    const char* __restrict__ Mq, const float* __restrict__ Sin,
    float* __restrict__ euo, float* __restrict__ ps)
{
    __shared__ float cps[4][NNODE];   // 32 KB per-wave column partials

    const int tid = threadIdx.x;
    const int lane = tid & 63, w = tid >> 6;
    const int b = blockIdx.y, chunk = blockIdx.x;
    const size_t row0 = ((size_t)b << 11) + chunk * 16;
    const char* gb = Mq + row0 * NNODE + lane * 16;

    // wv = 1/colsum at this thread's 32 cols (col = seg*1024 + lane*16 + k)
    float wv[32];
    if constexpr (FIRST) {
        #pragma unroll
        for (int k = 0; k < 32; ++k) wv[k] = 1.f;
    } else {
        const float* Sb = Sin + (b << 11);
        #pragma unroll
        for (int s = 0; s < 2; ++s)
            #pragma unroll
            for (int k = 0; k < 4; ++k) {
                const float4 vv = *(const float4*)(Sb + s * 1024 + lane * 16 + k * 4);
                wv[s*16+k*4+0] = 1.0f / vv.x;
                wv[s*16+k*4+1] = 1.0f / vv.y;
                wv[s*16+k*4+2] = 1.0f / vv.z;
                wv[s*16+k*4+3] = 1.0f / vv.w;
            }
    }

    float sc[32];
    #pragma unroll
    for (int k = 0; k < 32; ++k) sc[k] = 0.f;

    #pragma unroll
    for (int rr = 0; rr < 4; ++rr) {
        const char* rsrc = gb + (size_t)(w * 4 + rr) * NNODE;
        const int4 d0 = *(const int4*)(rsrc);
        const int4 d1 = *(const int4*)(rsrc + 1024);
        const unsigned qd[8] = {(unsigned)d0.x, (unsigned)d0.y, (unsigned)d0.z, (unsigned)d0.w,
                                (unsigned)d1.x, (unsigned)d1.y, (unsigned)d1.z, (unsigned)d1.w};
        float p[32];
        #pragma unroll
        for (int q = 0; q < 8; ++q)
            #pragma unroll
            for (int k = 0; k < 4; ++k)
                p[q * 4 + k] = exp2f(dqi(qd[q], k) * Q127);
        float s = 0.f;
        #pragma unroll
        for (int k = 0; k < 32; ++k) s = fmaf(p[k], wv[k], s);
        #pragma unroll
        for (int off = 1; off < 64; off <<= 1) s += __shfl_xor(s, off);
        const float eu = 1.0f / s;
        if (lane == 0) euo[row0 + w * 4 + rr] = eu;
        #pragma unroll
        for (int k = 0; k < 32; ++k) sc[k] = fmaf(p[k], eu, sc[k]);
    }

    #pragma unroll
    for (int s = 0; s < 2; ++s)
        #pragma unroll
        for (int k = 0; k < 4; ++k)
            *(float4*)(&cps[w][s * 1024 + lane * 16 + k * 4]) =
                make_float4(sc[s*16+k*4+0], sc[s*16+k*4+1], sc[s*16+k*4+2], sc[s*16+k*4+3]);
    __syncthreads();

    // block merge of 4 waves -> streamed partial store (coalesced, no RMW)
    const int j = tid * 8;
    float4 a0 = *(const float4*)(&cps[0][j]), a1 = *(const float4*)(&cps[0][j + 4]);
    #pragma unroll
    for (int ww = 1; ww < 4; ++ww) {
        const float4 b0 = *(const float4*)(&cps[ww][j]);
        const float4 b1 = *(const float4*)(&cps[ww][j + 4]);
        a0.x += b0.x; a0.y += b0.y; a0.z += b0.z; a0.w += b0.w;
        a1.x += b1.x; a1.y += b1.y; a1.z += b1.z; a1.w += b1.w;
    }
    float* dst = ps + ((size_t)(b * 128 + chunk)) * NNODE + j;
    *(float4*)dst = a0;
    *(float4*)(dst + 4) = a1;
}

// ---------------------------------------------------------------------------
// Kernel 4: colsum[b,j] = sum over 128 chunk partials   (no log)
// ---------------------------------------------------------------------------
__global__ __launch_bounds__(256) void cvgm_merge(
    const float* __restrict__ ps, float* __restrict__ colsum)
{
    const int idx = blockIdx.x * 256 + threadIdx.x;
    const int b = idx >> 11, j = idx & 2047;
    float s = 0.f;
    #pragma unroll 8
    for (int c = 0; c < 128; ++c) s += ps[(size_t)(b * 128 + c) * NNODE + j];
    colsum[idx] = s;
}

// ---------------------------------------------------------------------------
// Kernel 5: assignment = p * eu * wv -> out fp32; spart[row] partial score.
// Same stripe geometry as cvgm_rc: grid (128, 8), 256 threads.
// ---------------------------------------------------------------------------
__global__ __launch_bounds__(256) void cvgm_final(
    const char* __restrict__ Mq, const float* __restrict__ eui,
    const float* __restrict__ Scol, float* __restrict__ out,
    float* __restrict__ spart)
{
    const int tid = threadIdx.x;
    const int lane = tid & 63, w = tid >> 6;
    const int b = blockIdx.y, chunk = blockIdx.x;
    const size_t row0 = ((size_t)b << 11) + chunk * 16;
    const char* gb = Mq + row0 * NNODE + lane * 16;

    float wv[32];
    {
        const float* Sb = Scol + (b << 11);
        #pragma unroll
        for (int s = 0; s < 2; ++s)
            #pragma unroll
            for (int k = 0; k < 4; ++k) {
                const float4 vv = *(const float4*)(Sb + s * 1024 + lane * 16 + k * 4);
                wv[s*16+k*4+0] = 1.0f / vv.x;
                wv[s*16+k*4+1] = 1.0f / vv.y;
                wv[s*16+k*4+2] = 1.0f / vv.z;
                wv[s*16+k*4+3] = 1.0f / vv.w;
            }
    }

    #pragma unroll
    for (int rr = 0; rr < 4; ++rr) {
        const size_t row = row0 + w * 4 + rr;
        const char* rsrc = gb + (size_t)(w * 4 + rr) * NNODE;
        float* drow = out + row * NNODE + lane * 16;
        const float eu = eui[row];
        const int4 d0 = *(const int4*)(rsrc);
        const int4 d1 = *(const int4*)(rsrc + 1024);
        const unsigned qd[8] = {(unsigned)d0.x, (unsigned)d0.y, (unsigned)d0.z, (unsigned)d0.w,
                                (unsigned)d1.x, (unsigned)d1.y, (unsigned)d1.z, (unsigned)d1.w};
        float acc = 0.f;
        #pragma unroll
        for (int q = 0; q < 8; ++q) {
            float e[4];
            #pragma unroll
            for (int k = 0; k < 4; ++k) {
                const float xq = dqi(qd[q], k);
                e[k] = exp2f(xq * Q127) * eu * wv[q * 4 + k];
                acc = fmaf(e[k], xq, acc);
            }
            *(float4*)(drow + (q >> 2) * 1024 + (q & 3) * 4) = make_float4(e[0], e[1], e[2], e[3]);
        }
        #pragma unroll
        for (int off = 1; off < 64; off <<= 1) acc += __shfl_xor(acc, off);
        if (lane == 0) spart[row] = acc * INV127;
    }
}

// ---------------------------------------------------------------------------
// Kernel 6: match_score[b] = sum(spart[b,:]) / 2048
// ---------------------------------------------------------------------------
__global__ __launch_bounds__(256) void cvgm_score(
    const float* __restrict__ spart, float* __restrict__ score)
{
    const int b = blockIdx.x;
    float acc = 0.f;
    for (int t = threadIdx.x; t < NNODE; t += 256) acc += spart[(b << 11) + t];
    #pragma unroll
    for (int off = 1; off < 64; off <<= 1) acc += __shfl_xor(acc, off);
    __shared__ float sh[4];
    if ((threadIdx.x & 63) == 0) sh[threadIdx.x >> 6] = acc;
    __syncthreads();
    if (threadIdx.x == 0) score[b] = (sh[0] + sh[1] + sh[2] + sh[3]) * (1.0f / 2048.0f);
}

// ---------------------------------------------------------------------------
extern "C" void kernel_launch(void* const* d_in, const int* in_sizes, int n_in,
                              void* d_out, int out_size, void* d_ws, size_t ws_size,
                              hipStream_t stream) {
    (void)in_sizes; (void)n_in; (void)out_size; (void)ws_size;
    const float* drone = (const float*)d_in[0];
    const float* sat   = (const float*)d_in[1];
    const float* W     = (const float*)d_in[2];
    const float* bias  = (const float*)d_in[3];

    float* out   = (float*)d_out;
    float* score = out + (size_t)BATCH * NNODE * NNODE;

    char* ws = (char*)d_ws;
    const size_t SZ_M0Q  = (size_t)BATCH * NNODE * NNODE;       // 32 MiB
    const size_t SZ_PROJ = (size_t)ROWS_TOTAL * DM * 2;         // 8 MiB
    const size_t SZ_WT   = (size_t)DM * DIN * 2;                // 512 KiB
    const size_t SZ_UV   = (size_t)ROWS_TOTAL * 4;              // 64 KiB
    const size_t SZ_PS   = (size_t)BATCH * 128 * NNODE * 4;     // 8 MiB

    size_t off = 0;
    char* M0q  = ws + off;            off += SZ_M0Q;
    u16* dproj = (u16*)(ws + off);    off += SZ_PROJ;
    u16* sproj = (u16*)(ws + off);    off += SZ_PROJ;
    u16* Wt    = (u16*)(ws + off);    off += SZ_WT;
    float* colsum = (float*)(ws + off); off += SZ_UV;
    float* eu   = (float*)(ws + off); off += SZ_UV;
    float* ps   = (float*)(ws + off); off += SZ_PS;
    float* spart = (float*)(ws + off);

    cvgm_prep_w<<<dim3(32, 8), 256, 0, stream>>>(W, Wt);
    cvgm_proj_mfma<<<dim3(256, 2), 512, 0, stream>>>(drone, sat, Wt, bias, dproj, sproj);
    cvgm_m0_mfma<<<dim3(16, 16, 8), 256, 0, stream>>>(dproj, sproj, M0q);

    // 5 multiplicative Sinkhorn iterations: rc (row + col partials) + merge
    cvgm_rc<1><<<dim3(128, 8), 256, 0, stream>>>(M0q, colsum, eu, ps);
    cvgm_merge<<<ROWS_TOTAL / 256, 256, 0, stream>>>(ps, colsum);
    for (int it = 1; it < 5; ++it) {
        cvgm_rc<0><<<dim3(128, 8), 256, 0, stream>>>(M0q, colsum, eu, ps);
        cvgm_merge<<<ROWS_TOTAL / 256, 256, 0, stream>>>(ps, colsum);
    }

    cvgm_final<<<dim3(128, 8), 256, 0, stream>>>(M0q, eu, colsum, out, spart);
    cvgm_score<<<BATCH, 256, 0, stream>>>(spart, score);
}

// Round 11
// 261.273 us; speedup vs baseline: 2.1474x; 1.0002x over previous
//
#include <hip/hip_runtime.h>
#include <math.h>

#define BATCH 8
#define NNODE 2048
#define DIN   1024
#define DM    256
#define ROWS_TOTAL (BATCH * NNODE)   // 16384

#define Q127  0.011359803471566641f   // log2(e) / 127  ->  exp2(q*Q127) = e^(q/127)
#define INV127 0.007874015748031496f  // 1/127

typedef unsigned short u16;
typedef __attribute__((ext_vector_type(8))) short short8;   // 8 bf16
typedef __attribute__((ext_vector_type(4))) float f32x4;

// async global->LDS, 16B per lane; LDS dest = wave-uniform base + lane*16
#define GLD16(gp, lp) __builtin_amdgcn_global_load_lds( \
    (const __attribute__((address_space(1))) void*)(gp), \
    (__attribute__((address_space(3))) void*)(lp), 16, 0, 0)

__device__ __forceinline__ u16 f2b(float f) {   // fp32 -> bf16 RNE
    union { float f; unsigned u; } v; v.f = f;
    unsigned r = v.u + 0x7fffu + ((v.u >> 16) & 1u);
    return (u16)(r >> 16);
}
// signed byte k (0..3) of dword -> float
__device__ __forceinline__ float dqi(unsigned wd, int k) {
    return (float)((int)(wd << ((3 - k) * 8)) >> 24);
}

// ---------------------------------------------------------------------------
// Kernel 0: Wt[c][k] = bf16(W[k][c])
// ---------------------------------------------------------------------------
__global__ __launch_bounds__(256) void cvgm_prep_w(
    const float* __restrict__ W, u16* __restrict__ Wt)
{
    __shared__ float t[32][33];
    const int tx = threadIdx.x & 31, ty = threadIdx.x >> 5;
    const int k0 = blockIdx.x * 32, c0 = blockIdx.y * 32;
    #pragma unroll
    for (int r = 0; r < 4; ++r) {
        const int kl = ty * 4 + r;
        t[kl][tx] = W[(size_t)(k0 + kl) * DM + c0 + tx];
    }
    __syncthreads();
    #pragma unroll
    for (int r = 0; r < 4; ++r) {
        const int cl = ty * 4 + r;
        Wt[(size_t)(c0 + cl) * DIN + k0 + tx] = f2b(t[tx][cl]);
    }
}

// ---------------------------------------------------------------------------
// Kernel 1: P = bf16(l2norm(X@W + b)).  64 rows x 256 cols per block,
// 512 threads = 8 waves, BK=64.  grid (256, 2): y selects drone/sat.
// Bs staged via global_load_lds (linear LDS dest, pre-swizzled global src).
// ---------------------------------------------------------------------------
__global__ __launch_bounds__(512) void cvgm_proj_mfma(
    const float* __restrict__ Xd, const float* __restrict__ Xs,
    const u16* __restrict__ Wt, const float* __restrict__ bias,
    u16* __restrict__ Pd, u16* __restrict__ Ps)
{
    __shared__ u16 As[64 * 64];     // 8 KB  chunk-swizzled [row][k]
    __shared__ u16 Bs[256 * 64];    // 32 KB chunk-swizzled [col][k]
    __shared__ float rsum[4][64];

    const float* X = blockIdx.y ? Xs : Xd;
    u16* P = blockIdx.y ? Ps : Pd;

    const int tid = threadIdx.x;
    const int lane = tid & 63, wid = tid >> 6;
    const int wr = wid >> 2, wc = wid & 3;
    const int l15 = lane & 15, l4 = lane >> 4;
    const int row0 = blockIdx.x * 64;

    f32x4 acc[2][4];
    #pragma unroll
    for (int m = 0; m < 2; ++m)
        #pragma unroll
        for (int n = 0; n < 4; ++n) acc[m][n] = (f32x4){0.f, 0.f, 0.f, 0.f};

    const int arow = tid >> 3, ac = tid & 7;   // A: 1 short8 chunk / thread

    for (int k0 = 0; k0 < DIN; k0 += 64) {
        const float* src = X + (size_t)(row0 + arow) * DIN + k0 + ac * 8;
        const float4 x0 = *(const float4*)src;
        const float4 x1 = *(const float4*)(src + 4);
        __syncthreads();   // previous tile fully consumed
        // B staging: wave-linear LDS slots, swizzle folded into global addr
        #pragma unroll
        for (int i = 0; i < 4; ++i) {
            const int s = (wid * 4 + i) * 64 + lane;       // chunk slot 0..2047
            const int col = s >> 3, sc = s & 7;
            const int cc = sc ^ (col & 7);                 // involution
            GLD16(Wt + (size_t)col * DIN + k0 + cc * 8,
                  Bs + (size_t)((wid * 4 + i) * 64) * 8);
        }
        // A staging: convert f32->bf16, manual swizzled store
        short8 ap;
        ap[0]=(short)f2b(x0.x); ap[1]=(short)f2b(x0.y); ap[2]=(short)f2b(x0.z); ap[3]=(short)f2b(x0.w);
        ap[4]=(short)f2b(x1.x); ap[5]=(short)f2b(x1.y); ap[6]=(short)f2b(x1.z); ap[7]=(short)f2b(x1.w);
        *(short8*)(As + (arow * 8 + (ac ^ (arow & 7))) * 8) = ap;
        __syncthreads();   // drains vmcnt (gload_lds) + lgkmcnt (ds_write)
        #pragma unroll
        for (int ks = 0; ks < 2; ++ks) {
            const int ch = ks * 4 + l4;
            short8 af[2], bfr[4];
            #pragma unroll
            for (int m = 0; m < 2; ++m) {
                const int row = wr * 32 + m * 16 + l15;
                af[m] = *(const short8*)(As + (row * 8 + (ch ^ (row & 7))) * 8);
            }
            #pragma unroll
            for (int n = 0; n < 4; ++n) {
                const int col = wc * 64 + n * 16 + l15;
                bfr[n] = *(const short8*)(Bs + (col * 8 + (ch ^ (col & 7))) * 8);
            }
            #pragma unroll
            for (int m = 0; m < 2; ++m)
                #pragma unroll
                for (int n = 0; n < 4; ++n)
                    acc[m][n] = __builtin_amdgcn_mfma_f32_16x16x32_bf16(af[m], bfr[n], acc[m][n], 0, 0, 0);
        }
    }

    #pragma unroll
    for (int n = 0; n < 4; ++n) {
        const float bv = bias[wc * 64 + n * 16 + l15];
        #pragma unroll
        for (int m = 0; m < 2; ++m)
            #pragma unroll
            for (int r = 0; r < 4; ++r) acc[m][n][r] += bv;
    }
    #pragma unroll
    for (int m = 0; m < 2; ++m)
        #pragma unroll
        for (int r = 0; r < 4; ++r) {
            float s = 0.f;
            #pragma unroll
            for (int n = 0; n < 4; ++n) s += acc[m][n][r] * acc[m][n][r];
            s += __shfl_xor(s, 1); s += __shfl_xor(s, 2);
            s += __shfl_xor(s, 4); s += __shfl_xor(s, 8);
            if (l15 == 0) rsum[wc][wr * 32 + m * 16 + l4 * 4 + r] = s;
        }
    __syncthreads();
    #pragma unroll
    for (int m = 0; m < 2; ++m)
        #pragma unroll
        for (int r = 0; r < 4; ++r) {
            const int row = wr * 32 + m * 16 + l4 * 4 + r;
            const float tot = rsum[0][row] + rsum[1][row] + rsum[2][row] + rsum[3][row];
            const float inv = 1.0f / fmaxf(sqrtf(tot), 1e-12f);
            #pragma unroll
            for (int n = 0; n < 4; ++n) {
                const int col = wc * 64 + n * 16 + l15;
                P[(size_t)(row0 + row) * DM + col] = f2b(acc[m][n][r] * inv);
            }
        }
}

// ---------------------------------------------------------------------------
// Kernel 2: M0q[b] = int8( 127 * D[b]@S[b]^T )  bf16 MFMA 128x128 tile.
// Both operands staged via global_load_lds; int8 output packed through LDS
// and written as coalesced 16B stores (replaces 64 byte-stores/thread).
// ---------------------------------------------------------------------------
__global__ __launch_bounds__(256) void cvgm_m0_mfma(
    const u16* __restrict__ Dp, const u16* __restrict__ Sp,
    char* __restrict__ Cq)
{
    __shared__ u16 As[128 * 64];   // 16 KB
    __shared__ u16 Bs[128 * 64];   // 16 KB

    const int tid = threadIdx.x;
    const int lane = tid & 63, wid = tid >> 6;
    const int wr = wid >> 1, wc = wid & 1;
    const int l15 = lane & 15, l4 = lane >> 4;
    const int bb = blockIdx.z;
    const int i0 = blockIdx.y * 128, j0 = blockIdx.x * 128;
    const u16* Db = Dp + (size_t)bb * NNODE * DM;
    const u16* Sb = Sp + (size_t)bb * NNODE * DM;

    f32x4 acc[4][4];
    #pragma unroll
    for (int m = 0; m < 4; ++m)
        #pragma unroll
        for (int n = 0; n < 4; ++n) acc[m][n] = (f32x4){0.f, 0.f, 0.f, 0.f};

    for (int k0 = 0; k0 < DM; k0 += 64) {
        __syncthreads();   // previous tile fully consumed
        #pragma unroll
        for (int i = 0; i < 4; ++i) {
            const int s = (wid * 4 + i) * 64 + lane;       // chunk slot 0..1023
            const int row = s >> 3, sc = s & 7;
            const int cc = sc ^ (row & 7);                 // involution
            GLD16(Db + (size_t)(i0 + row) * DM + k0 + cc * 8,
                  As + (size_t)((wid * 4 + i) * 64) * 8);
            GLD16(Sb + (size_t)(j0 + row) * DM + k0 + cc * 8,
                  Bs + (size_t)((wid * 4 + i) * 64) * 8);
        }
        __syncthreads();   // drains vmcnt before LDS reads
        #pragma unroll
        for (int ks = 0; ks < 2; ++ks) {
            const int ch = ks * 4 + l4;
            short8 af[4], bfr[4];
            #pragma unroll
            for (int m = 0; m < 4; ++m) {
                const int row = wr * 64 + m * 16 + l15;
                af[m] = *(const short8*)(As + (row * 8 + (ch ^ (row & 7))) * 8);
            }
            #pragma unroll
            for (int n = 0; n < 4; ++n) {
                const int col = wc * 64 + n * 16 + l15;
                bfr[n] = *(const short8*)(Bs + (col * 8 + (ch ^ (col & 7))) * 8);
            }
            #pragma unroll
            for (int m = 0; m < 4; ++m)
                #pragma unroll
                for (int n = 0; n < 4; ++n)
                    acc[m][n] = __builtin_amdgcn_mfma_f32_16x16x32_bf16(af[m], bfr[n], acc[m][n], 0, 0, 0);
        }
    }

    // epilogue: quantize -> LDS char tile (reuse As) -> coalesced 16B stores
    __syncthreads();                    // all LDS reads done; safe to reuse
    char* Cs = (char*)As;               // 128*128 = 16 KB
    #pragma unroll
    for (int m = 0; m < 4; ++m) {
        const int rl = wr * 64 + m * 16 + l4 * 4;
        #pragma unroll
        for (int n = 0; n < 4; ++n) {
            const int cl = wc * 64 + n * 16 + l15;
            #pragma unroll
            for (int r = 0; r < 4; ++r) {
                int q = __float2int_rn(acc[m][n][r] * 127.f);
                q = q > 127 ? 127 : (q < -127 ? -127 : q);
                Cs[(rl + r) * 128 + cl] = (char)q;
            }
        }
    }
    __syncthreads();
    char* Cqb = Cq + (size_t)bb * NNODE * NNODE;
    const int lrow = tid >> 1, lcol = (tid & 1) * 64;
    #pragma unroll
    for (int i = 0; i < 4; ++i) {
        const int4 v = *(const int4*)(Cs + lrow * 128 + lcol + i * 16);
        *(int4*)(Cqb + (size_t)(i0 + lrow) * NNODE + j0 + lcol + i * 16) = v;
    }
}

// ---------------------------------------------------------------------------
// Kernel 3: one Sinkhorn iteration, multiplicative (no logs), ps-buffer
// reduction.  grid (128, 8), 256 threads, 16-row stripe per block.
// ---------------------------------------------------------------------------
template <int FIRST>
__global__ __launch_bounds__(256) void cvgm_rc(
    const char* __restrict__ Mq, const float* __restrict__ Sin,
    float* __restrict__ euo, float* __restrict__ ps)
{
    __shared__ float cps[4][NNODE];   // 32 KB per-wave column partials

    const int tid = threadIdx.x;
    const int lane = tid & 63, w = tid >> 6;
    const int b = blockIdx.y, chunk = blockIdx.x;
    const size_t row0 = ((size_t)b << 11) + chunk * 16;
    const char* gb = Mq + row0 * NNODE + lane * 16;

    float wv[32];
    if constexpr (FIRST) {
        #pragma unroll
        for (int k = 0; k < 32; ++k) wv[k] = 1.f;
    } else {
        const float* Sb = Sin + (b << 11);
        #pragma unroll
        for (int s = 0; s < 2; ++s)
            #pragma unroll
            for (int k = 0; k < 4; ++k) {
                const float4 vv = *(const float4*)(Sb + s * 1024 + lane * 16 + k * 4);
                wv[s*16+k*4+0] = 1.0f / vv.x;
                wv[s*16+k*4+1] = 1.0f / vv.y;
                wv[s*16+k*4+2] = 1.0f / vv.z;
                wv[s*16+k*4+3] = 1.0f / vv.w;
            }
    }

    float sc[32];
    #pragma unroll
    for (int k = 0; k < 32; ++k) sc[k] = 0.f;

    #pragma unroll
    for (int rr = 0; rr < 4; ++rr) {
        const char* rsrc = gb + (size_t)(w * 4 + rr) * NNODE;
        const int4 d0 = *(const int4*)(rsrc);
        const int4 d1 = *(const int4*)(rsrc + 1024);
        const unsigned qd[8] = {(unsigned)d0.x, (unsigned)d0.y, (unsigned)d0.z, (unsigned)d0.w,
                                (unsigned)d1.x, (unsigned)d1.y, (unsigned)d1.z, (unsigned)d1.w};
        float p[32];
        #pragma unroll
        for (int q = 0; q < 8; ++q)
            #pragma unroll
            for (int k = 0; k < 4; ++k)
                p[q * 4 + k] = exp2f(dqi(qd[q], k) * Q127);
        float s = 0.f;
        #pragma unroll
        for (int k = 0; k < 32; ++k) s = fmaf(p[k], wv[k], s);
        #pragma unroll
        for (int off = 1; off < 64; off <<= 1) s += __shfl_xor(s, off);
        const float eu = 1.0f / s;
        if (lane == 0) euo[row0 + w * 4 + rr] = eu;
        #pragma unroll
        for (int k = 0; k < 32; ++k) sc[k] = fmaf(p[k], eu, sc[k]);
    }

    #pragma unroll
    for (int s = 0; s < 2; ++s)
        #pragma unroll
        for (int k = 0; k < 4; ++k)
            *(float4*)(&cps[w][s * 1024 + lane * 16 + k * 4]) =
                make_float4(sc[s*16+k*4+0], sc[s*16+k*4+1], sc[s*16+k*4+2], sc[s*16+k*4+3]);
    __syncthreads();

    const int j = tid * 8;
    float4 a0 = *(const float4*)(&cps[0][j]), a1 = *(const float4*)(&cps[0][j + 4]);
    #pragma unroll
    for (int ww = 1; ww < 4; ++ww) {
        const float4 b0 = *(const float4*)(&cps[ww][j]);
        const float4 b1 = *(const float4*)(&cps[ww][j + 4]);
        a0.x += b0.x; a0.y += b0.y; a0.z += b0.z; a0.w += b0.w;
        a1.x += b1.x; a1.y += b1.y; a1.z += b1.z; a1.w += b1.w;
    }
    float* dst = ps + ((size_t)(b * 128 + chunk)) * NNODE + j;
    *(float4*)dst = a0;
    *(float4*)(dst + 4) = a1;
}

// ---------------------------------------------------------------------------
// Kernel 4: colsum[b,j] = sum over 128 chunk partials
// ---------------------------------------------------------------------------
__global__ __launch_bounds__(256) void cvgm_merge(
    const float* __restrict__ ps, float* __restrict__ colsum)
{
    const int idx = blockIdx.x * 256 + threadIdx.x;
    const int b = idx >> 11, j = idx & 2047;
    float s = 0.f;
    #pragma unroll 8
    for (int c = 0; c < 128; ++c) s += ps[(size_t)(b * 128 + c) * NNODE + j];
    colsum[idx] = s;
}

// ---------------------------------------------------------------------------
// Kernel 5: assignment = p * eu * wv -> out fp32; spart[row] partial score.
// ---------------------------------------------------------------------------
__global__ __launch_bounds__(256) void cvgm_final(
    const char* __restrict__ Mq, const float* __restrict__ eui,
    const float* __restrict__ Scol, float* __restrict__ out,
    float* __restrict__ spart)
{
    const int tid = threadIdx.x;
    const int lane = tid & 63, w = tid >> 6;
    const int b = blockIdx.y, chunk = blockIdx.x;
    const size_t row0 = ((size_t)b << 11) + chunk * 16;
    const char* gb = Mq + row0 * NNODE + lane * 16;

    float wv[32];
    {
        const float* Sb = Scol + (b << 11);
        #pragma unroll
        for (int s = 0; s < 2; ++s)
            #pragma unroll
            for (int k = 0; k < 4; ++k) {
                const float4 vv = *(const float4*)(Sb + s * 1024 + lane * 16 + k * 4);
                wv[s*16+k*4+0] = 1.0f / vv.x;
                wv[s*16+k*4+1] = 1.0f / vv.y;
                wv[s*16+k*4+2] = 1.0f / vv.z;
                wv[s*16+k*4+3] = 1.0f / vv.w;
            }
    }

    #pragma unroll
    for (int rr = 0; rr < 4; ++rr) {
        const size_t row = row0 + w * 4 + rr;
        const char* rsrc = gb + (size_t)(w * 4 + rr) * NNODE;
        float* drow = out + row * NNODE + lane * 16;
        const float eu = eui[row];
        const int4 d0 = *(const int4*)(rsrc);
        const int4 d1 = *(const int4*)(rsrc + 1024);
        const unsigned qd[8] = {(unsigned)d0.x, (unsigned)d0.y, (unsigned)d0.z, (unsigned)d0.w,
                                (unsigned)d1.x, (unsigned)d1.y, (unsigned)d1.z, (unsigned)d1.w};
        float acc = 0.f;
        #pragma unroll
        for (int q = 0; q < 8; ++q) {
            float e[4];
            #pragma unroll
            for (int k = 0; k < 4; ++k) {
                const float xq = dqi(qd[q], k);
                e[k] = exp2f(xq * Q127) * eu * wv[q * 4 + k];
                acc = fmaf(e[k], xq, acc);
            }
            *(float4*)(drow + (q >> 2) * 1024 + (q & 3) * 4) = make_float4(e[0], e[1], e[2], e[3]);
        }
        #pragma unroll
        for (int off = 1; off < 64; off <<= 1) acc += __shfl_xor(acc, off);
        if (lane == 0) spart[row] = acc * INV127;
    }
}

// ---------------------------------------------------------------------------
// Kernel 6: match_score[b] = sum(spart[b,:]) / 2048
// ---------------------------------------------------------------------------
__global__ __launch_bounds__(256) void cvgm_score(
    const float* __restrict__ spart, float* __restrict__ score)
{
    const int b = blockIdx.x;
    float acc = 0.f;
    for (int t = threadIdx.x; t < NNODE; t += 256) acc += spart[(b << 11) + t];
    #pragma unroll
    for (int off = 1; off < 64; off <<= 1) acc += __shfl_xor(acc, off);
    __shared__ float sh[4];
    if ((threadIdx.x & 63) == 0) sh[threadIdx.x >> 6] = acc;
    __syncthreads();
    if (threadIdx.x == 0) score[b] = (sh[0] + sh[1] + sh[2] + sh[3]) * (1.0f / 2048.0f);
}

// ---------------------------------------------------------------------------
extern "C" void kernel_launch(void* const* d_in, const int* in_sizes, int n_in,
                              void* d_out, int out_size, void* d_ws, size_t ws_size,
                              hipStream_t stream) {
    (void)in_sizes; (void)n_in; (void)out_size; (void)ws_size;
    const float* drone = (const float*)d_in[0];
    const float* sat   = (const float*)d_in[1];
    const float* W     = (const float*)d_in[2];
    const float* bias  = (const float*)d_in[3];

    float* out   = (float*)d_out;
    float* score = out + (size_t)BATCH * NNODE * NNODE;

    char* ws = (char*)d_ws;
    const size_t SZ_M0Q  = (size_t)BATCH * NNODE * NNODE;       // 32 MiB
    const size_t SZ_PROJ = (size_t)ROWS_TOTAL * DM * 2;         // 8 MiB
    const size_t SZ_WT   = (size_t)DM * DIN * 2;                // 512 KiB
    const size_t SZ_UV   = (size_t)ROWS_TOTAL * 4;              // 64 KiB
    const size_t SZ_PS   = (size_t)BATCH * 128 * NNODE * 4;     // 8 MiB

    size_t off = 0;
    char* M0q  = ws + off;            off += SZ_M0Q;
    u16* dproj = (u16*)(ws + off);    off += SZ_PROJ;
    u16* sproj = (u16*)(ws + off);    off += SZ_PROJ;
    u16* Wt    = (u16*)(ws + off);    off += SZ_WT;
    float* colsum = (float*)(ws + off); off += SZ_UV;
    float* eu   = (float*)(ws + off); off += SZ_UV;
    float* ps   = (float*)(ws + off); off += SZ_PS;
    float* spart = (float*)(ws + off);

    cvgm_prep_w<<<dim3(32, 8), 256, 0, stream>>>(W, Wt);
    cvgm_proj_mfma<<<dim3(256, 2), 512, 0, stream>>>(drone, sat, Wt, bias, dproj, sproj);
    cvgm_m0_mfma<<<dim3(16, 16, 8), 256, 0, stream>>>(dproj, sproj, M0q);

    // 5 multiplicative Sinkhorn iterations: rc (row + col partials) + merge
    cvgm_rc<1><<<dim3(128, 8), 256, 0, stream>>>(M0q, colsum, eu, ps);
    cvgm_merge<<<ROWS_TOTAL / 256, 256, 0, stream>>>(ps, colsum);
    for (int it = 1; it < 5; ++it) {
        cvgm_rc<0><<<dim3(128, 8), 256, 0, stream>>>(M0q, colsum, eu, ps);
        cvgm_merge<<<ROWS_TOTAL / 256, 256, 0, stream>>>(ps, colsum);
    }

    cvgm_final<<<dim3(128, 8), 256, 0, stream>>>(M0q, eu, colsum, out, spart);
    cvgm_score<<<BATCH, 256, 0, stream>>>(spart, score);
}

// Round 12
// 261.173 us; speedup vs baseline: 2.1482x; 1.0004x over previous
//
#include <hip/hip_runtime.h>
#include <math.h>

#define BATCH 8
#define NNODE 2048
#define DIN   1024
#define DM    256
#define ROWS_TOTAL (BATCH * NNODE)   // 16384

#define Q127  0.011359803471566641f   // log2(e) / 127  ->  exp2(q*Q127) = e^(q/127)
#define INV127 0.007874015748031496f  // 1/127

typedef unsigned short u16;
typedef __attribute__((ext_vector_type(8))) short short8;   // 8 bf16
typedef __attribute__((ext_vector_type(4))) float f32x4;

// async global->LDS, 16B per lane; LDS dest = wave-uniform base + lane*16
#define GLD16(gp, lp) __builtin_amdgcn_global_load_lds( \
    (const __attribute__((address_space(1))) void*)(gp), \
    (__attribute__((address_space(3))) void*)(lp), 16, 0, 0)

__device__ __forceinline__ u16 f2b(float f) {   // fp32 -> bf16 RNE
    union { float f; unsigned u; } v; v.f = f;
    unsigned r = v.u + 0x7fffu + ((v.u >> 16) & 1u);
    return (u16)(r >> 16);
}
// signed byte k (0..3) of dword -> float
__device__ __forceinline__ float dqi(unsigned wd, int k) {
    return (float)((int)(wd << ((3 - k) * 8)) >> 24);
}

// ---------------------------------------------------------------------------
// Kernel 0: Wt[c][k] = bf16(W[k][c])
// ---------------------------------------------------------------------------
__global__ __launch_bounds__(256) void cvgm_prep_w(
    const float* __restrict__ W, u16* __restrict__ Wt)
{
    __shared__ float t[32][33];
    const int tx = threadIdx.x & 31, ty = threadIdx.x >> 5;
    const int k0 = blockIdx.x * 32, c0 = blockIdx.y * 32;
    #pragma unroll
    for (int r = 0; r < 4; ++r) {
        const int kl = ty * 4 + r;
        t[kl][tx] = W[(size_t)(k0 + kl) * DM + c0 + tx];
    }
    __syncthreads();
    #pragma unroll
    for (int r = 0; r < 4; ++r) {
        const int cl = ty * 4 + r;
        Wt[(size_t)(c0 + cl) * DIN + k0 + tx] = f2b(t[tx][cl]);
    }
}

// ---------------------------------------------------------------------------
// Kernel 1: P = bf16(l2norm(X@W + b)).  64 rows x 256 cols per block,
// 512 threads = 8 waves, BK=64.  grid (256, 2): y selects drone/sat.
// ---------------------------------------------------------------------------
__global__ __launch_bounds__(512) void cvgm_proj_mfma(
    const float* __restrict__ Xd, const float* __restrict__ Xs,
    const u16* __restrict__ Wt, const float* __restrict__ bias,
    u16* __restrict__ Pd, u16* __restrict__ Ps)
{
    __shared__ u16 As[64 * 64];     // 8 KB  chunk-swizzled [row][k]
    __shared__ u16 Bs[256 * 64];    // 32 KB chunk-swizzled [col][k]
    __shared__ float rsum[4][64];

    const float* X = blockIdx.y ? Xs : Xd;
    u16* P = blockIdx.y ? Ps : Pd;

    const int tid = threadIdx.x;
    const int lane = tid & 63, wid = tid >> 6;
    const int wr = wid >> 2, wc = wid & 3;
    const int l15 = lane & 15, l4 = lane >> 4;
    const int row0 = blockIdx.x * 64;

    f32x4 acc[2][4];
    #pragma unroll
    for (int m = 0; m < 2; ++m)
        #pragma unroll
        for (int n = 0; n < 4; ++n) acc[m][n] = (f32x4){0.f, 0.f, 0.f, 0.f};

    const int arow = tid >> 3, ac = tid & 7;   // A: 1 short8 chunk / thread

    for (int k0 = 0; k0 < DIN; k0 += 64) {
        const float* src = X + (size_t)(row0 + arow) * DIN + k0 + ac * 8;
        const float4 x0 = *(const float4*)src;
        const float4 x1 = *(const float4*)(src + 4);
        __syncthreads();   // previous tile fully consumed
        #pragma unroll
        for (int i = 0; i < 4; ++i) {
            const int s = (wid * 4 + i) * 64 + lane;       // chunk slot 0..2047
            const int col = s >> 3, sc = s & 7;
            const int cc = sc ^ (col & 7);                 // involution
            GLD16(Wt + (size_t)col * DIN + k0 + cc * 8,
                  Bs + (size_t)((wid * 4 + i) * 64) * 8);
        }
        short8 ap;
        ap[0]=(short)f2b(x0.x); ap[1]=(short)f2b(x0.y); ap[2]=(short)f2b(x0.z); ap[3]=(short)f2b(x0.w);
        ap[4]=(short)f2b(x1.x); ap[5]=(short)f2b(x1.y); ap[6]=(short)f2b(x1.z); ap[7]=(short)f2b(x1.w);
        *(short8*)(As + (arow * 8 + (ac ^ (arow & 7))) * 8) = ap;
        __syncthreads();   // drains vmcnt (gload_lds) + lgkmcnt (ds_write)
        #pragma unroll
        for (int ks = 0; ks < 2; ++ks) {
            const int ch = ks * 4 + l4;
            short8 af[2], bfr[4];
            #pragma unroll
            for (int m = 0; m < 2; ++m) {
                const int row = wr * 32 + m * 16 + l15;
                af[m] = *(const short8*)(As + (row * 8 + (ch ^ (row & 7))) * 8);
            }
            #pragma unroll
            for (int n = 0; n < 4; ++n) {
                const int col = wc * 64 + n * 16 + l15;
                bfr[n] = *(const short8*)(Bs + (col * 8 + (ch ^ (col & 7))) * 8);
            }
            #pragma unroll
            for (int m = 0; m < 2; ++m)
                #pragma unroll
                for (int n = 0; n < 4; ++n)
                    acc[m][n] = __builtin_amdgcn_mfma_f32_16x16x32_bf16(af[m], bfr[n], acc[m][n], 0, 0, 0);
        }
    }

    #pragma unroll
    for (int n = 0; n < 4; ++n) {
        const float bv = bias[wc * 64 + n * 16 + l15];
        #pragma unroll
        for (int m = 0; m < 2; ++m)
            #pragma unroll
            for (int r = 0; r < 4; ++r) acc[m][n][r] += bv;
    }
    #pragma unroll
    for (int m = 0; m < 2; ++m)
        #pragma unroll
        for (int r = 0; r < 4; ++r) {
            float s = 0.f;
            #pragma unroll
            for (int n = 0; n < 4; ++n) s += acc[m][n][r] * acc[m][n][r];
            s += __shfl_xor(s, 1); s += __shfl_xor(s, 2);
            s += __shfl_xor(s, 4); s += __shfl_xor(s, 8);
            if (l15 == 0) rsum[wc][wr * 32 + m * 16 + l4 * 4 + r] = s;
        }
    __syncthreads();
    #pragma unroll
    for (int m = 0; m < 2; ++m)
        #pragma unroll
        for (int r = 0; r < 4; ++r) {
            const int row = wr * 32 + m * 16 + l4 * 4 + r;
            const float tot = rsum[0][row] + rsum[1][row] + rsum[2][row] + rsum[3][row];
            const float inv = 1.0f / fmaxf(sqrtf(tot), 1e-12f);
            #pragma unroll
            for (int n = 0; n < 4; ++n) {
                const int col = wc * 64 + n * 16 + l15;
                P[(size_t)(row0 + row) * DM + col] = f2b(acc[m][n][r] * inv);
            }
        }
}

// ---------------------------------------------------------------------------
// Kernel 2: M0q[b] = int8( 127 * D[b]@S[b]^T )  bf16 MFMA 128x128 tile.
// ---------------------------------------------------------------------------
__global__ __launch_bounds__(256) void cvgm_m0_mfma(
    const u16* __restrict__ Dp, const u16* __restrict__ Sp,
    char* __restrict__ Cq)
{
    __shared__ u16 As[128 * 64];   // 16 KB
    __shared__ u16 Bs[128 * 64];   // 16 KB

    const int tid = threadIdx.x;
    const int lane = tid & 63, wid = tid >> 6;
    const int wr = wid >> 1, wc = wid & 1;
    const int l15 = lane & 15, l4 = lane >> 4;
    const int bb = blockIdx.z;
    const int i0 = blockIdx.y * 128, j0 = blockIdx.x * 128;
    const u16* Db = Dp + (size_t)bb * NNODE * DM;
    const u16* Sb = Sp + (size_t)bb * NNODE * DM;

    f32x4 acc[4][4];
    #pragma unroll
    for (int m = 0; m < 4; ++m)
        #pragma unroll
        for (int n = 0; n < 4; ++n) acc[m][n] = (f32x4){0.f, 0.f, 0.f, 0.f};

    for (int k0 = 0; k0 < DM; k0 += 64) {
        __syncthreads();   // previous tile fully consumed
        #pragma unroll
        for (int i = 0; i < 4; ++i) {
            const int s = (wid * 4 + i) * 64 + lane;       // chunk slot 0..1023
            const int row = s >> 3, sc = s & 7;
            const int cc = sc ^ (row & 7);                 // involution
            GLD16(Db + (size_t)(i0 + row) * DM + k0 + cc * 8,
                  As + (size_t)((wid * 4 + i) * 64) * 8);
            GLD16(Sb + (size_t)(j0 + row) * DM + k0 + cc * 8,
                  Bs + (size_t)((wid * 4 + i) * 64) * 8);
        }
        __syncthreads();   // drains vmcnt before LDS reads
        #pragma unroll
        for (int ks = 0; ks < 2; ++ks) {
            const int ch = ks * 4 + l4;
            short8 af[4], bfr[4];
            #pragma unroll
            for (int m = 0; m < 4; ++m) {
                const int row = wr * 64 + m * 16 + l15;
                af[m] = *(const short8*)(As + (row * 8 + (ch ^ (row & 7))) * 8);
            }
            #pragma unroll
            for (int n = 0; n < 4; ++n) {
                const int col = wc * 64 + n * 16 + l15;
                bfr[n] = *(const short8*)(Bs + (col * 8 + (ch ^ (col & 7))) * 8);
            }
            #pragma unroll
            for (int m = 0; m < 4; ++m)
                #pragma unroll
                for (int n = 0; n < 4; ++n)
                    acc[m][n] = __builtin_amdgcn_mfma_f32_16x16x32_bf16(af[m], bfr[n], acc[m][n], 0, 0, 0);
        }
    }

    // epilogue: quantize -> LDS char tile (reuse As) -> coalesced 16B stores
    __syncthreads();
    char* Cs = (char*)As;               // 128*128 = 16 KB
    #pragma unroll
    for (int m = 0; m < 4; ++m) {
        const int rl = wr * 64 + m * 16 + l4 * 4;
        #pragma unroll
        for (int n = 0; n < 4; ++n) {
            const int cl = wc * 64 + n * 16 + l15;
            #pragma unroll
            for (int r = 0; r < 4; ++r) {
                int q = __float2int_rn(acc[m][n][r] * 127.f);
                q = q > 127 ? 127 : (q < -127 ? -127 : q);
                Cs[(rl + r) * 128 + cl] = (char)q;
            }
        }
    }
    __syncthreads();
    char* Cqb = Cq + (size_t)bb * NNODE * NNODE;
    const int lrow = tid >> 1, lcol = (tid & 1) * 64;
    #pragma unroll
    for (int i = 0; i < 4; ++i) {
        const int4 v = *(const int4*)(Cs + lrow * 128 + lcol + i * 16);
        *(int4*)(Cqb + (size_t)(i0 + lrow) * NNODE + j0 + lcol + i * 16) = v;
    }
}

// ---------------------------------------------------------------------------
// Kernel 3: one Sinkhorn iteration, multiplicative, ps-buffer reduction.
// grid (128, 8), 256 threads, 16-row stripe per block.
// Row loads software-pipelined: rows 0,1 issued up front; row rr+1 issued
// before row rr is processed (hides ~250cy L3 latency under exp2/butterfly).
// ---------------------------------------------------------------------------
template <int FIRST>
__global__ __launch_bounds__(256) void cvgm_rc(
    const char* __restrict__ Mq, const float* __restrict__ Sin,
    float* __restrict__ euo, float* __restrict__ ps)
{
    __shared__ float cps[4][NNODE];   // 32 KB per-wave column partials

    const int tid = threadIdx.x;
    const int lane = tid & 63, w = tid >> 6;
    const int b = blockIdx.y, chunk = blockIdx.x;
    const size_t row0 = ((size_t)b << 11) + chunk * 16;
    const char* r0 = Mq + (row0 + w * 4) * NNODE + lane * 16;

    // rows 0,1 in flight immediately
    const int4 a0 = *(const int4*)(r0);
    const int4 b0 = *(const int4*)(r0 + 1024);
    const int4 a1 = *(const int4*)(r0 + NNODE);
    const int4 b1 = *(const int4*)(r0 + NNODE + 1024);

    float wv[32];
    if constexpr (FIRST) {
        #pragma unroll
        for (int k = 0; k < 32; ++k) wv[k] = 1.f;
    } else {
        const float* Sb = Sin + (b << 11);
        #pragma unroll
        for (int s = 0; s < 2; ++s)
            #pragma unroll
            for (int k = 0; k < 4; ++k) {
                const float4 vv = *(const float4*)(Sb + s * 1024 + lane * 16 + k * 4);
                wv[s*16+k*4+0] = 1.0f / vv.x;
                wv[s*16+k*4+1] = 1.0f / vv.y;
                wv[s*16+k*4+2] = 1.0f / vv.z;
                wv[s*16+k*4+3] = 1.0f / vv.w;
            }
    }

    float sc[32];
    #pragma unroll
    for (int k = 0; k < 32; ++k) sc[k] = 0.f;

    auto process = [&](const int4& da, const int4& db, int rr) {
        const unsigned qd[8] = {(unsigned)da.x, (unsigned)da.y, (unsigned)da.z, (unsigned)da.w,
                                (unsigned)db.x, (unsigned)db.y, (unsigned)db.z, (unsigned)db.w};
        float p[32];
        #pragma unroll
        for (int q = 0; q < 8; ++q)
            #pragma unroll
            for (int k = 0; k < 4; ++k)
                p[q * 4 + k] = exp2f(dqi(qd[q], k) * Q127);
        float s = 0.f;
        #pragma unroll
        for (int k = 0; k < 32; ++k) s = fmaf(p[k], wv[k], s);
        #pragma unroll
        for (int off = 1; off < 64; off <<= 1) s += __shfl_xor(s, off);
        const float eu = 1.0f / s;
        if (lane == 0) euo[row0 + w * 4 + rr] = eu;
        #pragma unroll
        for (int k = 0; k < 32; ++k) sc[k] = fmaf(p[k], eu, sc[k]);
    };

    // prefetch row 2, process row 0; prefetch row 3, process row 1; ...
    const int4 a2 = *(const int4*)(r0 + 2 * NNODE);
    const int4 b2 = *(const int4*)(r0 + 2 * NNODE + 1024);
    process(a0, b0, 0);
    const int4 a3 = *(const int4*)(r0 + 3 * NNODE);
    const int4 b3 = *(const int4*)(r0 + 3 * NNODE + 1024);
    process(a1, b1, 1);
    process(a2, b2, 2);
    process(a3, b3, 3);

    #pragma unroll
    for (int s = 0; s < 2; ++s)
        #pragma unroll
        for (int k = 0; k < 4; ++k)
            *(float4*)(&cps[w][s * 1024 + lane * 16 + k * 4]) =
                make_float4(sc[s*16+k*4+0], sc[s*16+k*4+1], sc[s*16+k*4+2], sc[s*16+k*4+3]);
    __syncthreads();

    const int j = tid * 8;
    float4 s0 = *(const float4*)(&cps[0][j]), s1 = *(const float4*)(&cps[0][j + 4]);
    #pragma unroll
    for (int ww = 1; ww < 4; ++ww) {
        const float4 t0 = *(const float4*)(&cps[ww][j]);
        const float4 t1 = *(const float4*)(&cps[ww][j + 4]);
        s0.x += t0.x; s0.y += t0.y; s0.z += t0.z; s0.w += t0.w;
        s1.x += t1.x; s1.y += t1.y; s1.z += t1.z; s1.w += t1.w;
    }
    float* dst = ps + ((size_t)(b * 128 + chunk)) * NNODE + j;
    *(float4*)dst = s0;
    *(float4*)(dst + 4) = s1;
}

// ---------------------------------------------------------------------------
// Kernel 4: colsum[b,j] = sum over 128 chunk partials
// ---------------------------------------------------------------------------
__global__ __launch_bounds__(256) void cvgm_merge(
    const float* __restrict__ ps, float* __restrict__ colsum)
{
    const int idx = blockIdx.x * 256 + threadIdx.x;
    const int b = idx >> 11, j = idx & 2047;
    float s = 0.f;
    #pragma unroll 8
    for (int c = 0; c < 128; ++c) s += ps[(size_t)(b * 128 + c) * NNODE + j];
    colsum[idx] = s;
}

// ---------------------------------------------------------------------------
// Kernel 5: assignment = p * eu * wv -> out fp32; spart[row] partial score.
// 8-row stripes, grid (256, 8) = 2048 blocks, NO LDS -> 8 blocks/CU,
// 32 waves/CU (full occupancy).  Both rows' loads issued up front.
// ---------------------------------------------------------------------------
__global__ __launch_bounds__(256) void cvgm_final(
    const char* __restrict__ Mq, const float* __restrict__ eui,
    const float* __restrict__ Scol, float* __restrict__ out,
    float* __restrict__ spart)
{
    const int tid = threadIdx.x;
    const int lane = tid & 63, w = tid >> 6;
    const int b = blockIdx.y, chunk = blockIdx.x;
    const size_t row0 = ((size_t)b << 11) + chunk * 8;   // 8-row stripe
    const char* r0 = Mq + (row0 + w * 2) * NNODE + lane * 16;

    // both rows' M0 loads in flight immediately
    const int4 a0 = *(const int4*)(r0);
    const int4 b0 = *(const int4*)(r0 + 1024);
    const int4 a1 = *(const int4*)(r0 + NNODE);
    const int4 b1 = *(const int4*)(r0 + NNODE + 1024);
    const float eu0 = eui[row0 + w * 2];
    const float eu1 = eui[row0 + w * 2 + 1];

    float wv[32];
    {
        const float* Sb = Scol + (b << 11);
        #pragma unroll
        for (int s = 0; s < 2; ++s)
            #pragma unroll
            for (int k = 0; k < 4; ++k) {
                const float4 vv = *(const float4*)(Sb + s * 1024 + lane * 16 + k * 4);
                wv[s*16+k*4+0] = 1.0f / vv.x;
                wv[s*16+k*4+1] = 1.0f / vv.y;
                wv[s*16+k*4+2] = 1.0f / vv.z;
                wv[s*16+k*4+3] = 1.0f / vv.w;
            }
    }

    auto emit = [&](const int4& da, const int4& db, int rr, float eu) {
        const size_t row = row0 + w * 2 + rr;
        float* drow = out + row * NNODE + lane * 16;
        const unsigned qd[8] = {(unsigned)da.x, (unsigned)da.y, (unsigned)da.z, (unsigned)da.w,
                                (unsigned)db.x, (unsigned)db.y, (unsigned)db.z, (unsigned)db.w};
        float acc = 0.f;
        #pragma unroll
        for (int q = 0; q < 8; ++q) {
            float e[4];
            #pragma unroll
            for (int k = 0; k < 4; ++k) {
                const float xq = dqi(qd[q], k);
                e[k] = exp2f(xq * Q127) * eu * wv[q * 4 + k];
                acc = fmaf(e[k], xq, acc);
            }
            *(float4*)(drow + (q >> 2) * 1024 + (q & 3) * 4) = make_float4(e[0], e[1], e[2], e[3]);
        }
        #pragma unroll
        for (int off = 1; off < 64; off <<= 1) acc += __shfl_xor(acc, off);
        if (lane == 0) spart[row] = acc * INV127;
    };

    emit(a0, b0, 0, eu0);
    emit(a1, b1, 1, eu1);
}

// ---------------------------------------------------------------------------
// Kernel 6: match_score[b] = sum(spart[b,:]) / 2048
// ---------------------------------------------------------------------------
__global__ __launch_bounds__(256) void cvgm_score(
    const float* __restrict__ spart, float* __restrict__ score)
{
    const int b = blockIdx.x;
    float acc = 0.f;
    for (int t = threadIdx.x; t < NNODE; t += 256) acc += spart[(b << 11) + t];
    #pragma unroll
    for (int off = 1; off < 64; off <<= 1) acc += __shfl_xor(acc, off);
    __shared__ float sh[4];
    if ((threadIdx.x & 63) == 0) sh[threadIdx.x >> 6] = acc;
    __syncthreads();
    if (threadIdx.x == 0) score[b] = (sh[0] + sh[1] + sh[2] + sh[3]) * (1.0f / 2048.0f);
}

// ---------------------------------------------------------------------------
extern "C" void kernel_launch(void* const* d_in, const int* in_sizes, int n_in,
                              void* d_out, int out_size, void* d_ws, size_t ws_size,
                              hipStream_t stream) {
    (void)in_sizes; (void)n_in; (void)out_size; (void)ws_size;
    const float* drone = (const float*)d_in[0];
    const float* sat   = (const float*)d_in[1];
    const float* W     = (const float*)d_in[2];
    const float* bias  = (const float*)d_in[3];

    float* out   = (float*)d_out;
    float* score = out + (size_t)BATCH * NNODE * NNODE;

    char* ws = (char*)d_ws;
    const size_t SZ_M0Q  = (size_t)BATCH * NNODE * NNODE;       // 32 MiB
    const size_t SZ_PROJ = (size_t)ROWS_TOTAL * DM * 2;         // 8 MiB
    const size_t SZ_WT   = (size_t)DM * DIN * 2;                // 512 KiB
    const size_t SZ_UV   = (size_t)ROWS_TOTAL * 4;              // 64 KiB
    const size_t SZ_PS   = (size_t)BATCH * 128 * NNODE * 4;     // 8 MiB

    size_t off = 0;
    char* M0q  = ws + off;            off += SZ_M0Q;
    u16* dproj = (u16*)(ws + off);    off += SZ_PROJ;
    u16* sproj = (u16*)(ws + off);    off += SZ_PROJ;
    u16* Wt    = (u16*)(ws + off);    off += SZ_WT;
    float* colsum = (float*)(ws + off); off += SZ_UV;
    float* eu   = (float*)(ws + off); off += SZ_UV;
    float* ps   = (float*)(ws + off); off += SZ_PS;
    float* spart = (float*)(ws + off);

    cvgm_prep_w<<<dim3(32, 8), 256, 0, stream>>>(W, Wt);
    cvgm_proj_mfma<<<dim3(256, 2), 512, 0, stream>>>(drone, sat, Wt, bias, dproj, sproj);
    cvgm_m0_mfma<<<dim3(16, 16, 8), 256, 0, stream>>>(dproj, sproj, M0q);

    // 5 multiplicative Sinkhorn iterations: rc (row + col partials) + merge
    cvgm_rc<1><<<dim3(128, 8), 256, 0, stream>>>(M0q, colsum, eu, ps);
    cvgm_merge<<<ROWS_TOTAL / 256, 256, 0, stream>>>(ps, colsum);
    for (int it = 1; it < 5; ++it) {
        cvgm_rc<0><<<dim3(128, 8), 256, 0, stream>>>(M0q, colsum, eu, ps);
        cvgm_merge<<<ROWS_TOTAL / 256, 256, 0, stream>>>(ps, colsum);
    }

    cvgm_final<<<dim3(256, 8), 256, 0, stream>>>(M0q, eu, colsum, out, spart);
    cvgm_score<<<BATCH, 256, 0, stream>>>(spart, score);
}